// Round 2
// baseline (1118.719 us; speedup 1.0000x reference)
//
#include <hip/hip_runtime.h>
#include <hip/hip_bf16.h>
#include <stdint.h>

// Problem constants
#define B_ 1024
#define T_ 64
#define D_ 256
#define H_ 256
#define G_ 1024   // 4*H

typedef float f32x4 __attribute__((ext_vector_type(4)));
typedef __bf16 bf16x8 __attribute__((ext_vector_type(8)));
typedef unsigned int u32x4 __attribute__((ext_vector_type(4)));

#if __has_builtin(__builtin_amdgcn_rcpf)
#define RCP(x) __builtin_amdgcn_rcpf(x)
#else
#define RCP(x) (1.f / (x))
#endif

__device__ __forceinline__ float bf2f(unsigned int u) {
    unsigned int x = u << 16;
    return __builtin_bit_cast(float, x);
}
__device__ __forceinline__ unsigned short f2bf(float f) {
    __hip_bfloat16 h = __float2bfloat16(f);   // RNE
    return __builtin_bit_cast(unsigned short, h);
}

// ---------------------------------------------------------------------------
// prep_w: W_ih, W_hh f32 -> bf16 (row-major, same layout); bias = b_ih + b_hh
__global__ void prep_w_kernel(const float* __restrict__ Wih, const float* __restrict__ Whh,
                              const float* __restrict__ bih, const float* __restrict__ bhh,
                              unsigned short* __restrict__ wih_bf, unsigned short* __restrict__ whh_bf,
                              float* __restrict__ bias) {
    int i = blockIdx.x * 256 + threadIdx.x;   // covers G_*D_ exactly
    wih_bf[i] = f2bf(Wih[i]);
    whh_bf[i] = f2bf(Whh[i]);
    if (i < G_) bias[i] = bih[i] + bhh[i];
}

// ---------------------------------------------------------------------------
// prep_attn: x_score[b,d] = sum_t x[b,t,d]*w_x[t];  attn[b,:] = softmax_d(x_score)
// (s_hc and b_attn cancel in the softmax). grid 1024 blocks x 256 threads.
__global__ void prep_attn_kernel(const float* __restrict__ x, const float* __restrict__ Wattn,
                                 float* __restrict__ attn) {
    __shared__ float wx[T_];
    __shared__ float red[256];
    int b = blockIdx.x, d = threadIdx.x;
    if (d < T_) wx[d] = Wattn[2 * H_ + d];
    __syncthreads();
    const float* xb = x + (size_t)b * T_ * D_ + d;
    float s = 0.f;
    #pragma unroll
    for (int t = 0; t < T_; ++t) s += xb[t * D_] * wx[t];
    red[d] = s;
    __syncthreads();
    for (int o = 128; o > 0; o >>= 1) {
        if (d < o) red[d] = fmaxf(red[d], red[d + o]);
        __syncthreads();
    }
    float m = red[0];
    __syncthreads();
    float e = __expf(s - m);
    red[d] = e;
    __syncthreads();
    for (int o = 128; o > 0; o >>= 1) {
        if (d < o) red[d] += red[d + o];
        __syncthreads();
    }
    attn[b * D_ + d] = e * (1.f / red[0]);
}

// ---------------------------------------------------------------------------
// winw: w_in = attn (*) x. Writes f32 output 0 ([b][t][d]) and bf16 copy in
// t-major layout [t][b][d] for the GEMM.
__global__ void winw_kernel(const float* __restrict__ x, const float* __restrict__ attn,
                            float* __restrict__ w_out, unsigned short* __restrict__ win_bf) {
    int i4 = blockIdx.x * 256 + threadIdx.x;  // [0, B*T*D/4)
    int e  = i4 * 4;
    int d  = e & 255;
    int bt = e >> 8;            // b*64 + t
    int b  = bt >> 6, t = bt & 63;
    f32x4 xv = *(const f32x4*)(x + e);
    f32x4 av = *(const f32x4*)(attn + b * D_ + d);
    f32x4 w  = xv * av;
    *(f32x4*)(w_out + e) = w;
    ushort4 u;
    u.x = f2bf(w[0]); u.y = f2bf(w[1]); u.z = f2bf(w[2]); u.w = f2bf(w[3]);
    *(ushort4*)(win_bf + ((size_t)(t * B_ + b) * D_ + d)) = u;
}

// ---------------------------------------------------------------------------
// gemmx: pre_gates[m][n] = sum_k w_in[m][k] * W_ih[n][k], m = t*1024+b.
__global__ __launch_bounds__(256, 2) void gemmx_kernel(const unsigned short* __restrict__ A,
                                                       const unsigned short* __restrict__ Bw,
                                                       unsigned short* __restrict__ pre) {
    int bx = blockIdx.x;               // 4096 = 512 x 8
    int bn = bx & 7, bm = bx >> 3;
    int tid = threadIdx.x, lane = tid & 63, w = tid >> 6;
    int wr = w >> 1, wc = w & 1;
    int m0 = bm * 128 + wr * 64, n0 = bn * 128 + wc * 64;
    int lr = lane & 15, lk = (lane >> 4) * 8;

    const unsigned short* Ab[4];
    const unsigned short* Bb[4];
    #pragma unroll
    for (int i = 0; i < 4; ++i) {
        Ab[i] = A  + (size_t)(m0 + i * 16 + lr) * D_ + lk;
        Bb[i] = Bw + (size_t)(n0 + i * 16 + lr) * D_ + lk;
    }
    f32x4 acc[4][4] = {};
    #pragma unroll
    for (int kk = 0; kk < 8; ++kk) {
        bf16x8 a[4], bb[4];
        #pragma unroll
        for (int i = 0; i < 4; ++i) {
            a[i]  = *(const bf16x8*)(Ab[i] + kk * 32);
            bb[i] = *(const bf16x8*)(Bb[i] + kk * 32);
        }
        #pragma unroll
        for (int mi = 0; mi < 4; ++mi)
            #pragma unroll
            for (int ni = 0; ni < 4; ++ni)
                acc[mi][ni] = __builtin_amdgcn_mfma_f32_16x16x32_bf16(a[mi], bb[ni], acc[mi][ni], 0, 0, 0);
    }
    int orow = (lane >> 4) * 4;
    #pragma unroll
    for (int mi = 0; mi < 4; ++mi)
        #pragma unroll
        for (int ni = 0; ni < 4; ++ni)
            #pragma unroll
            for (int q = 0; q < 4; ++q) {
                int m = m0 + mi * 16 + orow + q;
                int n = n0 + ni * 16 + lr;
                pre[(size_t)m * G_ + n] = f2bf(acc[mi][ni][q]);
            }
}

// ---------------------------------------------------------------------------
// seqs: sequential LSTM, 64 blocks x 512 threads (8 waves), 16 batch rows per
// block. Distance-4 software pipeline on the W_hh stream: 4 kk-slots of B
// fragments live in registers; each kk consumes one slot and immediately
// re-issues its load for kk+4 (same address every step -> the kk>=4 reissues
// prefetch the NEXT step, overlapping the cell update + barriers). An empty
// asm "+v" launder on the W offsets blocks LICM from hoisting the stream
// (which would need 256 VGPRs). pre gates are loaded directly from global
// (u16) at step top, hidden under the K-loop. Raw lgkmcnt(0)+s_barrier keeps
// in-flight global loads alive across barriers (no vmcnt(0) drain).
__global__ __launch_bounds__(512, 2) void seqs_kernel(const unsigned short* __restrict__ pre,
                                                      const unsigned short* __restrict__ Whh,
                                                      const float* __restrict__ bias,
                                                      float* __restrict__ enc_out) {
    __shared__ unsigned short h_lds[16 * 264];     // pitch 264: b128 reads ~conflict-free
    int tid = threadIdx.x, lane = tid & 63, w = tid >> 6;
    int lr = lane & 15, hi = lane >> 4;
    int r0 = blockIdx.x * 16;
    int jbase = w * 32;

    for (int i = tid; i < 16 * 264; i += 512) h_lds[i] = 0;

    float c[2][4] = {};
    float bias_r[2][4];
    unsigned int off[2][4];    // W_hh byte offsets per tile (laundered each step)
    #pragma unroll
    for (int jt = 0; jt < 2; ++jt)
        #pragma unroll
        for (int g = 0; g < 4; ++g) {
            int n = g * 256 + jbase + jt * 16 + lr;
            bias_r[jt][g] = bias[n];
            off[jt][g] = (unsigned)(n * 256 + hi * 8) * 2;   // n*512 + hi*16 bytes
        }
    const char* Wb = (const char*)Whh;

    // prefetch W fragment slots kk=0..3 (128 VGPRs, stay live across t-loop)
    u32x4 bf[4][2][4];
    #pragma unroll
    for (int s = 0; s < 4; ++s)
        #pragma unroll
        for (int jt = 0; jt < 2; ++jt)
            #pragma unroll
            for (int g = 0; g < 4; ++g)
                bf[s][jt][g] = *(const u32x4*)(Wb + off[jt][g] + s * 64);

    // per-q voffsets for the pre-gate loads (imm offset covers g,jt)
    unsigned int poff[4];
    #pragma unroll
    for (int q = 0; q < 4; ++q)
        poff[q] = (unsigned)(((hi * 4 + q) * G_ + jbase + lr) * 2);

    __syncthreads();

    #pragma unroll 1
    for (int t = 0; t < T_; ++t) {
        // launder W offsets: defeats cross-iteration CSE/LICM of the W stream
        asm volatile("" : "+v"(off[0][0]), "+v"(off[0][1]), "+v"(off[0][2]), "+v"(off[0][3]),
                          "+v"(off[1][0]), "+v"(off[1][1]), "+v"(off[1][2]), "+v"(off[1][3]));

        // pre_gates[t] direct loads (32 u16/thread), hidden under K-loop
        unsigned int preg[2][4][4];
        const char* Ps = (const char*)pre + ((size_t)t * B_ + r0) * G_ * 2;
        #pragma unroll
        for (int q = 0; q < 4; ++q)
            #pragma unroll
            for (int g = 0; g < 4; ++g)
                #pragma unroll
                for (int jt = 0; jt < 2; ++jt)
                    preg[jt][g][q] = *(const unsigned short*)(Ps + poff[q] + (g * 256 + jt * 16) * 2);

        // K-loop: gates_h = h @ W_hh^T with distance-4 load pipeline
        f32x4 acc[2][4] = {};
        #pragma unroll
        for (int kk = 0; kk < 8; ++kk) {
            bf16x8 a = *(const bf16x8*)&h_lds[lr * 264 + kk * 32 + hi * 8];
            #pragma unroll
            for (int jt = 0; jt < 2; ++jt)
                #pragma unroll
                for (int g = 0; g < 4; ++g)
                    acc[jt][g] = __builtin_amdgcn_mfma_f32_16x16x32_bf16(
                        a, __builtin_bit_cast(bf16x8, bf[kk & 3][jt][g]), acc[jt][g], 0, 0, 0);
            // re-issue this slot's load for kk+4 (kk>=4 -> next step's kk-4)
            #pragma unroll
            for (int jt = 0; jt < 2; ++jt)
                #pragma unroll
                for (int g = 0; g < 4; ++g)
                    bf[kk & 3][jt][g] = *(const u32x4*)(Wb + off[jt][g] + (((kk + 4) & 7) * 64));
        }

        // barrier A: all waves' h_lds reads done (lgkm only; W loads stay in flight)
        asm volatile("s_waitcnt lgkmcnt(0)" ::: "memory");
        __builtin_amdgcn_s_barrier();

        // cell update (f32)
        #pragma unroll
        for (int jt = 0; jt < 2; ++jt) {
            int j = jbase + jt * 16 + lr;
            #pragma unroll
            for (int q = 0; q < 4; ++q) {
                int m = hi * 4 + q;
                float gi = acc[jt][0][q] + bf2f(preg[jt][0][q]) + bias_r[jt][0];
                float gf = acc[jt][1][q] + bf2f(preg[jt][1][q]) + bias_r[jt][1];
                float gg = acc[jt][2][q] + bf2f(preg[jt][2][q]) + bias_r[jt][2];
                float go = acc[jt][3][q] + bf2f(preg[jt][3][q]) + bias_r[jt][3];
                float si = RCP(1.f + __expf(-gi));
                float sf = RCP(1.f + __expf(-gf));
                float so = RCP(1.f + __expf(-go));
                float tg = 1.f - 2.f * RCP(__expf(2.f * gg) + 1.f);
                float cn = sf * c[jt][q] + si * tg;
                c[jt][q] = cn;
                float tc = 1.f - 2.f * RCP(__expf(2.f * cn) + 1.f);
                float h  = so * tc;
                h_lds[m * 264 + j] = f2bf(h);
                enc_out[((size_t)(r0 + m) * T_ + t) * H_ + j] = h;
            }
        }

        // barrier B: h_lds writes visible before next step's reads
        asm volatile("s_waitcnt lgkmcnt(0)" ::: "memory");
        __builtin_amdgcn_s_barrier();
    }
}

// ---------------------------------------------------------------------------
extern "C" void kernel_launch(void* const* d_in, const int* in_sizes, int n_in,
                              void* d_out, int out_size, void* d_ws, size_t ws_size,
                              hipStream_t stream) {
    const float* x     = (const float*)d_in[0];
    const float* Wattn = (const float*)d_in[1];
    // d_in[2] = b_attn (cancels in softmax)
    const float* Wih   = (const float*)d_in[3];
    const float* Whh   = (const float*)d_in[4];
    const float* bih   = (const float*)d_in[5];
    const float* bhh   = (const float*)d_in[6];

    char* ws = (char*)d_ws;
    float*          attn   = (float*)(ws);                            // 1 MB
    unsigned short* win_bf = (unsigned short*)(ws + 1048576);         // 32 MB [t][b][d]
    unsigned short* wih_bf = (unsigned short*)(ws + 34603008);        // 512 KB
    unsigned short* whh_bf = (unsigned short*)(ws + 35127296);        // 512 KB
    float*          bias   = (float*)(ws + 35651584);                 // 4 KB
    unsigned short* pre    = (unsigned short*)(ws + 35655680);        // 128 MB [t][b][n]

    float* w_out   = (float*)d_out;                                   // output 0
    float* enc_out = (float*)d_out + (size_t)B_ * T_ * D_;            // output 1

    prep_w_kernel<<<dim3(1024), dim3(256), 0, stream>>>(Wih, Whh, bih, bhh, wih_bf, whh_bf, bias);
    prep_attn_kernel<<<dim3(1024), dim3(256), 0, stream>>>(x, Wattn, attn);
    winw_kernel<<<dim3(16384), dim3(256), 0, stream>>>(x, attn, w_out, win_bf);
    gemmx_kernel<<<dim3(4096), dim3(256), 0, stream>>>(win_bf, wih_bf, pre);
    seqs_kernel<<<dim3(64), dim3(512), 0, stream>>>(pre, whh_bf, bias, enc_out);
}